// Round 2
// baseline (396.874 us; speedup 1.0000x reference)
//
#include <hip/hip_runtime.h>

// VertexUpdate: out[i] = (b_i, x_i, b_i - sum_{e:src[e]=i} c_e)
//
// R1: device atomicAdd scatter -> 771 us; WRITE 500 MB (16M x 32B sectors).
// R4: radix binning, cursor scatter -> 640 us (partition WRITE 455 MB).
// R5: LDS counting-sort + linear copy-out -> 429 us.
// R6: TPB 1024, register-staged int4/float4 loads, ulonglong2 aggregate
//     reads + LDS-staged float4 output -> 401 us.
// R7: shuffle wave-scan (18 barriers -> 3/5), early eattr loads, aggregate
//     4-deep MLP -> 390 us. Partition 118 us @ 26% HBM, VALUBusy 10%:
//     still latency-bound. __syncthreads drains vmcnt(0) -> per-tile
//     serial {load-burst, wait, LDS phases} with HBM idle between bursts.
// R8: persistent blocks (grid=512, 2/CU) grid-striding tiles; register
//     prefetch of tile k+1 during tile k; raw s_barrier + lgkmcnt(0)-only
//     waits so prefetch loads stay in flight across barriers (T3/T4);
//     strided scalar loads (8x src dword + 8x eattr.y dword) to fit
//     2-tile register state under 64 VGPR; alloc[] atomic issued before
//     the scan so its latency hides there.
//     Predict: partition ~75 us @ ~3.3 TB/s, total ~345 us.

#define BSHIFT 11
#define BSIZE (1 << BSHIFT)      // 2048 vertices per bucket
#define NBUCK_PAD 512            // padded bucket count (real: 489)
#define TILE 8192
#define TPB 1024
#define PGRID 512                // persistent blocks: 2 per CU

// Barrier that does NOT drain vmcnt: LDS ordering only. Prefetch global
// loads stay in flight across it (compiler emits counted vmcnt before
// first use of the loaded registers).
#define BARL() do { \
    asm volatile("s_waitcnt lgkmcnt(0)" ::: "memory"); \
    __builtin_amdgcn_s_barrier(); } while (0)

__global__ __launch_bounds__(TPB, 8)
void vu_partition(const int* __restrict__ src,
                  const float* __restrict__ eattr,
                  unsigned long long* __restrict__ pairs,
                  unsigned int* __restrict__ alloc,
                  int ne, int nbuck, int cap) {
    __shared__ unsigned long long sorted[TILE];   // 64 KB
    __shared__ unsigned int hist[NBUCK_PAD];
    __shared__ unsigned int base_l[NBUCK_PAD];
    __shared__ unsigned int cursor[NBUCK_PAD];
    __shared__ unsigned int gbase[NBUCK_PAD];
    __shared__ unsigned int wsum[8];              // per-wave scan sums
    __shared__ unsigned int wexcl[8];             // exclusive wave offsets

    const int t = threadIdx.x;
    const int nt_tiles = (ne + TILE - 1) / TILE;

    // Current-tile register state: thread t owns edges tile0 + k*1024 + t.
    int   s0, s1, s2, s3, s4, s5, s6, s7;
    float c0, c1, c2, c3, c4, c5, c6, c7;

    int tk = blockIdx.x;

    // prologue: load first tile (if full)
    if (tk < nt_tiles) {
        int tile0 = tk * TILE;
        if (tile0 + TILE <= ne) {
            const int* sp = src + tile0 + t;
            const float* cp = eattr + 2 * (tile0 + t) + 1;
            s0 = sp[0 * 1024]; s1 = sp[1 * 1024];
            s2 = sp[2 * 1024]; s3 = sp[3 * 1024];
            s4 = sp[4 * 1024]; s5 = sp[5 * 1024];
            s6 = sp[6 * 1024]; s7 = sp[7 * 1024];
            c0 = cp[0 * 2048]; c1 = cp[1 * 2048];
            c2 = cp[2 * 2048]; c3 = cp[3 * 2048];
            c4 = cp[4 * 2048]; c5 = cp[5 * 2048];
            c6 = cp[6 * 2048]; c7 = cp[7 * 2048];
        }
    }
    if (t < NBUCK_PAD) hist[t] = 0u;
    BARL();

    for (; tk < nt_tiles; tk += PGRID) {
        int tile0 = tk * TILE;
        int lim = ne - tile0; if (lim > TILE) lim = TILE;
        bool full = (lim == TILE);

        // --- prefetch next tile into fresh registers (stays in flight
        //     across all barriers below; consumed next iteration) ---
        int nk = tk + PGRID;
        bool pv = (nk < nt_tiles) && (nk * TILE + TILE <= ne);
        int   p0s, p1s, p2s, p3s, p4s, p5s, p6s, p7s;
        float p0c, p1c, p2c, p3c, p4c, p5c, p6c, p7c;
        if (pv) {
            int ptile0 = nk * TILE;
            const int* sp = src + ptile0 + t;
            const float* cp = eattr + 2 * (ptile0 + t) + 1;
            p0s = sp[0 * 1024]; p1s = sp[1 * 1024];
            p2s = sp[2 * 1024]; p3s = sp[3 * 1024];
            p4s = sp[4 * 1024]; p5s = sp[5 * 1024];
            p6s = sp[6 * 1024]; p7s = sp[7 * 1024];
            p0c = cp[0 * 2048]; p1c = cp[1 * 2048];
            p2c = cp[2 * 2048]; p3c = cp[3 * 2048];
            p4c = cp[4 * 2048]; p5c = cp[5 * 2048];
            p6c = cp[6 * 2048]; p7c = cp[7 * 2048];
        }

        // --- 1) histogram (from current registers) ---
        if (full) {
            atomicAdd(&hist[((unsigned)s0) >> BSHIFT], 1u);
            atomicAdd(&hist[((unsigned)s1) >> BSHIFT], 1u);
            atomicAdd(&hist[((unsigned)s2) >> BSHIFT], 1u);
            atomicAdd(&hist[((unsigned)s3) >> BSHIFT], 1u);
            atomicAdd(&hist[((unsigned)s4) >> BSHIFT], 1u);
            atomicAdd(&hist[((unsigned)s5) >> BSHIFT], 1u);
            atomicAdd(&hist[((unsigned)s6) >> BSHIFT], 1u);
            atomicAdd(&hist[((unsigned)s7) >> BSHIFT], 1u);
        } else {
            for (int i = t; i < lim; i += TPB)
                atomicAdd(&hist[((unsigned)src[tile0 + i]) >> BSHIFT], 1u);
        }
        BARL();                                   // B1: hist complete

        unsigned int mycnt = (t < NBUCK_PAD) ? hist[t] : 0u;
        if (t < NBUCK_PAD) hist[t] = 0u;          // re-zero for next tile
        // global allocation atomic issued NOW; latency hides under scan
        unsigned int gb = 0u;
        if (t < nbuck && mycnt) gb = atomicAdd(&alloc[t], mycnt);

        // --- 2) exclusive scan over 512 entries (shuffle wave-scan) ---
        unsigned int x = mycnt;
        #pragma unroll
        for (int off = 1; off < 64; off <<= 1) {
            unsigned int v = __shfl_up(x, off, 64);
            if ((t & 63) >= off) x += v;
        }
        if (t < NBUCK_PAD && (t & 63) == 63) wsum[t >> 6] = x;
        BARL();                                   // B2
        if (t < 8) {
            unsigned int s = 0u;
            for (int k = 0; k < t; ++k) s += wsum[k];
            wexcl[t] = s;
        }
        BARL();                                   // B3
        if (t < NBUCK_PAD) {
            unsigned int excl = x + wexcl[t >> 6] - mycnt;
            base_l[t] = excl;
            cursor[t] = excl;
            gbase[t] = gb;                        // waits on atomic here
        }
        BARL();                                   // B4: cursors ready

        // --- 3) scatter into LDS sorted by bucket ---
#define VU_SCAT(sv, cv) do { \
        unsigned int q_ = ((unsigned)(sv)) >> BSHIFT; \
        unsigned int pos_ = atomicAdd(&cursor[q_], 1u); \
        sorted[pos_] = ((unsigned long long)__float_as_uint(cv) << 32) \
                       | (unsigned)(sv); } while (0)
        if (full) {
            VU_SCAT(s0, c0); VU_SCAT(s1, c1);
            VU_SCAT(s2, c2); VU_SCAT(s3, c3);
            VU_SCAT(s4, c4); VU_SCAT(s5, c5);
            VU_SCAT(s6, c6); VU_SCAT(s7, c7);
        } else {
            for (int i = t; i < lim; i += TPB) {
                int e = tile0 + i;
                int s = src[e];
                float2 ec = ((const float2*)eattr)[e];
                VU_SCAT(s, ec.y);
            }
        }
#undef VU_SCAT
        BARL();                                   // B5: sorted ready

        // --- 4) linear copy-out: contiguous in LDS and global ---
        for (int i = t; i < lim; i += TPB) {
            unsigned long long p = sorted[i];
            unsigned int q = ((unsigned int)p) >> BSHIFT;
            unsigned int dst = q * (unsigned int)cap + gbase[q]
                             + ((unsigned int)i - base_l[q]);
            unsigned int hi = q * (unsigned int)cap + (unsigned int)cap - 1u;
            if (dst > hi) dst = hi;                // OOB guard (never fires)
            pairs[dst] = p;
        }
        // no barrier here: next iter's hist touches hist[] only (disjoint
        // from sorted/base_l/gbase); overwrites of those occur after B3/B4.

        // rotate prefetch registers into current
        s0 = p0s; s1 = p1s; s2 = p2s; s3 = p3s;
        s4 = p4s; s5 = p5s; s6 = p6s; s7 = p7s;
        c0 = p0c; c1 = p1c; c2 = p2c; c3 = p3c;
        c4 = p4c; c5 = p5c; c6 = p6c; c7 = p7c;
    }
}

__global__ __launch_bounds__(1024)
void vu_aggregate(const unsigned long long* __restrict__ pairs,
                  const unsigned int* __restrict__ alloc,
                  const float* __restrict__ vattr,
                  float* __restrict__ out,
                  int nv, int cap) {
    __shared__ float acc[BSIZE];                   // 8 KB
    __shared__ float obuf[BSIZE * 3];              // 24 KB
    int q = blockIdx.x;
    int t = threadIdx.x;
    acc[t] = 0.0f;
    acc[t + 1024] = 0.0f;

    // early vattr loads: latency hides under the pair loop
    int v0 = q << BSHIFT;
    int iv0 = v0 + t, iv1 = v0 + t + 1024;
    float2 va0 = make_float2(0.f, 0.f), va1 = make_float2(0.f, 0.f);
    if (iv0 < nv) va0 = ((const float2*)vattr)[iv0];
    if (iv1 < nv) va1 = ((const float2*)vattr)[iv1];
    __syncthreads();

    unsigned int cnt = alloc[q];
    if (cnt > (unsigned int)cap) cnt = (unsigned int)cap;
    const unsigned long long* p = pairs + (size_t)q * (size_t)cap;
    const ulonglong2* p2 = (const ulonglong2*)p;   // cap mult of 16 -> aligned
    unsigned int n2 = cnt >> 1;

#define VU_ACC(v64) do { \
        atomicAdd(&acc[((unsigned int)(v64)) & (BSIZE - 1)], \
                  __uint_as_float((unsigned int)((v64) >> 32))); } while (0)

    // 4-deep MLP: 4 independent 16B loads in flight per thread
    unsigned int i = t;
    for (; i + 3u * 1024u < n2; i += 4096u) {
        ulonglong2 v0 = p2[i];
        ulonglong2 v1 = p2[i + 1024u];
        ulonglong2 v2 = p2[i + 2048u];
        ulonglong2 v3 = p2[i + 3072u];
        VU_ACC(v0.x); VU_ACC(v0.y);
        VU_ACC(v1.x); VU_ACC(v1.y);
        VU_ACC(v2.x); VU_ACC(v2.y);
        VU_ACC(v3.x); VU_ACC(v3.y);
    }
    for (; i < n2; i += 1024u) {
        ulonglong2 v = p2[i];
        VU_ACC(v.x); VU_ACC(v.y);
    }
    if (t == 0 && (cnt & 1u)) {
        unsigned long long v = p[cnt - 1];
        VU_ACC(v);
    }
#undef VU_ACC
    __syncthreads();

    if (iv0 < nv) {
        obuf[3 * t + 0] = va0.x;
        obuf[3 * t + 1] = va0.y;
        obuf[3 * t + 2] = va0.x - acc[t];
    }
    {
        int i2 = t + 1024;
        if (iv1 < nv) {
            obuf[3 * i2 + 0] = va1.x;
            obuf[3 * i2 + 1] = va1.y;
            obuf[3 * i2 + 2] = va1.x - acc[i2];
        }
    }
    __syncthreads();

    // coalesced float4 write of the bucket's contiguous out-slice
    long fbase = (long)q * (BSIZE * 3);
    int nfl = 3 * nv - (int)fbase;
    if (nfl > BSIZE * 3) nfl = BSIZE * 3;
    if (nfl > 0) {
        float4* o4 = (float4*)(out + fbase);       // fbase mult of 4
        const float4* s4 = (const float4*)obuf;
        int n4 = nfl >> 2;
        for (int j = t; j < n4; j += 1024) o4[j] = s4[j];
        for (int j = (n4 << 2) + t; j < nfl; j += 1024) out[fbase + j] = obuf[j];
    }
}

// ---- fallback (round-1 path, 961 us) if ws is too small ----
__global__ void vu_init_kernel(const float* __restrict__ vattr,
                               float* __restrict__ out, int n) {
    int i = blockIdx.x * blockDim.x + threadIdx.x;
    if (i < n) {
        float2 v = ((const float2*)vattr)[i];
        out[3 * i + 0] = v.x;
        out[3 * i + 1] = v.y;
        out[3 * i + 2] = v.x;
    }
}

__global__ void vu_scatter_kernel(const int* __restrict__ src,
                                  const float* __restrict__ eattr,
                                  float* __restrict__ out, int ne) {
    int t = blockIdx.x * blockDim.x + threadIdx.x;
    int e0 = t * 4;
    if (e0 + 3 < ne) {
        int4 idx = ((const int4*)src)[t];
        float4 a = ((const float4*)eattr)[2 * t + 0];
        float4 b = ((const float4*)eattr)[2 * t + 1];
        atomicAdd(&out[3 * idx.x + 2], -a.y);
        atomicAdd(&out[3 * idx.y + 2], -a.w);
        atomicAdd(&out[3 * idx.z + 2], -b.y);
        atomicAdd(&out[3 * idx.w + 2], -b.w);
    } else {
        for (int e = e0; e < ne; ++e)
            atomicAdd(&out[3 * src[e] + 2], -eattr[2 * e + 1]);
    }
}

extern "C" void kernel_launch(void* const* d_in, const int* in_sizes, int n_in,
                              void* d_out, int out_size, void* d_ws, size_t ws_size,
                              hipStream_t stream) {
    const float* vattr = (const float*)d_in[0];
    const int* edges = (const int*)d_in[1];   // (2, N_E); row 0 = src
    const float* eattr = (const float*)d_in[2];
    float* out = (float*)d_out;

    int nv = in_sizes[0] / 2;   // 1,000,000
    int ne = in_sizes[2] / 2;   // 16,000,000

    int nbuck = (nv + BSIZE - 1) >> BSHIFT;          // 489
    int mean = ne / nbuck;                           // ~32.7K
    int cap = mean + mean / 8 + 1024;                // +~13% slack
    cap = (cap + 15) & ~15;

    size_t alloc_bytes = 4096;
    size_t pair_bytes = (size_t)nbuck * (size_t)cap * 8ull;
    size_t need = alloc_bytes + pair_bytes;          // ~145 MB

    if (ws_size >= need && nbuck <= NBUCK_PAD) {
        unsigned int* alloc = (unsigned int*)d_ws;
        unsigned long long* pairs = (unsigned long long*)((char*)d_ws + alloc_bytes);
        (void)hipMemsetAsync(alloc, 0, (size_t)nbuck * 4, stream);

        int nt_tiles = (ne + TILE - 1) / TILE;       // 1954
        int grid = PGRID; if (grid > nt_tiles) grid = nt_tiles;
        vu_partition<<<grid, TPB, 0, stream>>>(edges, eattr, pairs, alloc,
                                               ne, nbuck, cap);
        vu_aggregate<<<nbuck, 1024, 0, stream>>>(pairs, alloc, vattr, out, nv, cap);
    } else {
        int threads = 256;
        int blocks = (nv + threads - 1) / threads;
        vu_init_kernel<<<blocks, threads, 0, stream>>>(vattr, out, nv);
        int nt = (ne + 3) / 4;
        blocks = (nt + threads - 1) / threads;
        vu_scatter_kernel<<<blocks, threads, 0, stream>>>(edges, eattr, out, ne);
    }
}

// Round 3
// 373.324 us; speedup vs baseline: 1.0631x; 1.0631x over previous
//
#include <hip/hip_runtime.h>

// VertexUpdate: out[i] = (b_i, x_i, b_i - sum_{e:src[e]=i} c_e)
//
// R1: device atomicAdd scatter -> 771 us; WRITE 500 MB (16M x 32B sectors).
// R4: radix binning, cursor scatter -> 640 us (partition WRITE 455 MB).
// R5: LDS counting-sort + linear copy-out -> 429 us.
// R6: TPB 1024, register-staged vector loads, ulonglong2 aggregate -> 401 us.
// R7: shuffle wave-scan (18 barriers -> 5), early eattr loads -> 390 us.
//     Partition 118 us @ 26% HBM, VALUBusy 10%.
// R8: persistent blocks + cross-barrier register prefetch (loads issued a
//     full tile ahead) -> FLAT (119-121 us). Load latency is NOT the cost.
// R9: theory = contended device atomics on alloc[] (489 counters in ~31
//     cache lines, 956K RMWs from all 8 XCDs, line serialization at the
//     coherence point throttles every tile's gbase dependency; hiding
//     latency can't fix a throughput cap -> explains R8's null).
//     Fix: 8 replica counter sets + 8 replica pair regions, replica =
//     blockIdx&7 (matches round-robin block->XCD mapping; counter lines
//     become XCD-local, writers/counter drop 512->64). Aggregate sums 8
//     segments per bucket. Also: B3 removed (redundant wave-prefix
//     compute in all threads), 5 -> 4 barriers/tile.
//     Predict: partition ~65-80 us @ ~3.2 TB/s, total ~345 us; if flat,
//     next round is phase ablation with asm keepalives.

#define BSHIFT 11
#define BSIZE (1 << BSHIFT)      // 2048 vertices per bucket
#define NBUCK_PAD 512            // padded bucket count (real: 489)
#define TILE 8192
#define TPB 1024
#define PGRID 512                // persistent blocks: 2 per CU
#define NREP 8                   // replica sets (one per XCD)

// Barrier that does NOT drain vmcnt: LDS ordering only. Prefetch global
// loads stay in flight across it.
#define BARL() do { \
    asm volatile("s_waitcnt lgkmcnt(0)" ::: "memory"); \
    __builtin_amdgcn_s_barrier(); } while (0)

__global__ __launch_bounds__(TPB, 8)
void vu_partition(const int* __restrict__ src,
                  const float* __restrict__ eattr,
                  unsigned long long* __restrict__ pairs,
                  unsigned int* __restrict__ alloc,
                  int ne, int nbuck, int cap_r) {
    __shared__ unsigned long long sorted[TILE];   // 64 KB
    __shared__ unsigned int hist[NBUCK_PAD];
    __shared__ unsigned int base_l[NBUCK_PAD];
    __shared__ unsigned int cursor[NBUCK_PAD];
    __shared__ unsigned int gbase[NBUCK_PAD];
    __shared__ unsigned int wsum[8];              // per-wave scan sums

    const int t = threadIdx.x;
    const int rep = blockIdx.x & (NREP - 1);      // replica set (~XCD id)
    const int nt_tiles = (ne + TILE - 1) / TILE;

    // Current-tile register state: thread t owns edges tile0 + k*1024 + t.
    int   s0, s1, s2, s3, s4, s5, s6, s7;
    float c0, c1, c2, c3, c4, c5, c6, c7;

    int tk = blockIdx.x;

    // prologue: load first tile (if full)
    if (tk < nt_tiles) {
        int tile0 = tk * TILE;
        if (tile0 + TILE <= ne) {
            const int* sp = src + tile0 + t;
            const float* cp = eattr + 2 * (tile0 + t) + 1;
            s0 = sp[0 * 1024]; s1 = sp[1 * 1024];
            s2 = sp[2 * 1024]; s3 = sp[3 * 1024];
            s4 = sp[4 * 1024]; s5 = sp[5 * 1024];
            s6 = sp[6 * 1024]; s7 = sp[7 * 1024];
            c0 = cp[0 * 2048]; c1 = cp[1 * 2048];
            c2 = cp[2 * 2048]; c3 = cp[3 * 2048];
            c4 = cp[4 * 2048]; c5 = cp[5 * 2048];
            c6 = cp[6 * 2048]; c7 = cp[7 * 2048];
        }
    }
    if (t < NBUCK_PAD) hist[t] = 0u;
    BARL();

    for (; tk < nt_tiles; tk += PGRID) {
        int tile0 = tk * TILE;
        int lim = ne - tile0; if (lim > TILE) lim = TILE;
        bool full = (lim == TILE);

        // --- prefetch next tile (stays in flight across barriers) ---
        int nk = tk + PGRID;
        bool pv = (nk < nt_tiles) && (nk * TILE + TILE <= ne);
        int   p0s, p1s, p2s, p3s, p4s, p5s, p6s, p7s;
        float p0c, p1c, p2c, p3c, p4c, p5c, p6c, p7c;
        if (pv) {
            int ptile0 = nk * TILE;
            const int* sp = src + ptile0 + t;
            const float* cp = eattr + 2 * (ptile0 + t) + 1;
            p0s = sp[0 * 1024]; p1s = sp[1 * 1024];
            p2s = sp[2 * 1024]; p3s = sp[3 * 1024];
            p4s = sp[4 * 1024]; p5s = sp[5 * 1024];
            p6s = sp[6 * 1024]; p7s = sp[7 * 1024];
            p0c = cp[0 * 2048]; p1c = cp[1 * 2048];
            p2c = cp[2 * 2048]; p3c = cp[3 * 2048];
            p4c = cp[4 * 2048]; p5c = cp[5 * 2048];
            p6c = cp[6 * 2048]; p7c = cp[7 * 2048];
        }

        // --- 1) histogram (from current registers) ---
        if (full) {
            atomicAdd(&hist[((unsigned)s0) >> BSHIFT], 1u);
            atomicAdd(&hist[((unsigned)s1) >> BSHIFT], 1u);
            atomicAdd(&hist[((unsigned)s2) >> BSHIFT], 1u);
            atomicAdd(&hist[((unsigned)s3) >> BSHIFT], 1u);
            atomicAdd(&hist[((unsigned)s4) >> BSHIFT], 1u);
            atomicAdd(&hist[((unsigned)s5) >> BSHIFT], 1u);
            atomicAdd(&hist[((unsigned)s6) >> BSHIFT], 1u);
            atomicAdd(&hist[((unsigned)s7) >> BSHIFT], 1u);
        } else {
            for (int i = t; i < lim; i += TPB)
                atomicAdd(&hist[((unsigned)src[tile0 + i]) >> BSHIFT], 1u);
        }
        BARL();                                   // B1: hist complete

        unsigned int mycnt = (t < NBUCK_PAD) ? hist[t] : 0u;
        if (t < NBUCK_PAD) hist[t] = 0u;          // re-zero for next tile
        // replica-local allocation atomic (uncontended across XCDs)
        unsigned int gb = 0u;
        if (t < nbuck && mycnt)
            gb = atomicAdd(&alloc[rep * NBUCK_PAD + t], mycnt);

        // --- 2) exclusive scan over 512 entries (shuffle wave-scan) ---
        unsigned int x = mycnt;
        #pragma unroll
        for (int off = 1; off < 64; off <<= 1) {
            unsigned int v = __shfl_up(x, off, 64);
            if ((t & 63) >= off) x += v;
        }
        if (t < NBUCK_PAD && (t & 63) == 63) wsum[t >> 6] = x;
        BARL();                                   // B2: wsum ready

        // all threads compute their wave-prefix redundantly (broadcast
        // LDS reads are free) -> old B3 barrier removed
        unsigned int wx = 0u;
        int wid = t >> 6;
        #pragma unroll
        for (int k = 0; k < 7; ++k) {
            unsigned int w = wsum[k];
            if (k < wid) wx += w;
        }
        if (t < NBUCK_PAD) {
            unsigned int excl = x + wx - mycnt;
            base_l[t] = excl;
            cursor[t] = excl;
            gbase[t] = gb;                        // waits on atomic here
        }
        BARL();                                   // B4: cursors ready

        // --- 3) scatter into LDS sorted by bucket ---
#define VU_SCAT(sv, cv) do { \
        unsigned int q_ = ((unsigned)(sv)) >> BSHIFT; \
        unsigned int pos_ = atomicAdd(&cursor[q_], 1u); \
        sorted[pos_] = ((unsigned long long)__float_as_uint(cv) << 32) \
                       | (unsigned)(sv); } while (0)
        if (full) {
            VU_SCAT(s0, c0); VU_SCAT(s1, c1);
            VU_SCAT(s2, c2); VU_SCAT(s3, c3);
            VU_SCAT(s4, c4); VU_SCAT(s5, c5);
            VU_SCAT(s6, c6); VU_SCAT(s7, c7);
        } else {
            for (int i = t; i < lim; i += TPB) {
                int e = tile0 + i;
                int s = src[e];
                float2 ec = ((const float2*)eattr)[e];
                VU_SCAT(s, ec.y);
            }
        }
#undef VU_SCAT
        BARL();                                   // B5: sorted ready

        // --- 4) linear copy-out into this block's replica region ---
        for (int i = t; i < lim; i += TPB) {
            unsigned long long p = sorted[i];
            unsigned int q = ((unsigned int)p) >> BSHIFT;
            unsigned int seg = (q << 3) + (unsigned int)rep;  // q*NREP+rep
            unsigned int dst = seg * (unsigned int)cap_r + gbase[q]
                             + ((unsigned int)i - base_l[q]);
            unsigned int hi = seg * (unsigned int)cap_r + (unsigned int)cap_r - 1u;
            if (dst > hi) dst = hi;                // OOB guard (never fires)
            pairs[dst] = p;
        }
        // no barrier here: next iter's hist touches hist[] only.

        // rotate prefetch registers into current
        s0 = p0s; s1 = p1s; s2 = p2s; s3 = p3s;
        s4 = p4s; s5 = p5s; s6 = p6s; s7 = p7s;
        c0 = p0c; c1 = p1c; c2 = p2c; c3 = p3c;
        c4 = p4c; c5 = p5c; c6 = p6c; c7 = p7c;
    }
}

__global__ __launch_bounds__(1024)
void vu_aggregate(const unsigned long long* __restrict__ pairs,
                  const unsigned int* __restrict__ alloc,
                  const float* __restrict__ vattr,
                  float* __restrict__ out,
                  int nv, int cap_r) {
    __shared__ float acc[BSIZE];                   // 8 KB
    __shared__ float obuf[BSIZE * 3];              // 24 KB
    int q = blockIdx.x;
    int t = threadIdx.x;
    acc[t] = 0.0f;
    acc[t + 1024] = 0.0f;

    // early vattr loads: latency hides under the pair loops
    int v0 = q << BSHIFT;
    int iv0 = v0 + t, iv1 = v0 + t + 1024;
    float2 va0 = make_float2(0.f, 0.f), va1 = make_float2(0.f, 0.f);
    if (iv0 < nv) va0 = ((const float2*)vattr)[iv0];
    if (iv1 < nv) va1 = ((const float2*)vattr)[iv1];

    // preload all replica counts
    unsigned int cnts[NREP];
    #pragma unroll
    for (int r = 0; r < NREP; ++r) {
        unsigned int c = alloc[r * NBUCK_PAD + q];
        cnts[r] = (c > (unsigned int)cap_r) ? (unsigned int)cap_r : c;
    }
    __syncthreads();

#define VU_ACC(v64) do { \
        atomicAdd(&acc[((unsigned int)(v64)) & (BSIZE - 1)], \
                  __uint_as_float((unsigned int)((v64) >> 32))); } while (0)

    #pragma unroll
    for (int r = 0; r < NREP; ++r) {
        unsigned int cnt = cnts[r];
        const unsigned long long* p =
            pairs + (size_t)(q * NREP + r) * (size_t)cap_r;
        const ulonglong2* p2 = (const ulonglong2*)p;  // cap_r mult of 16
        unsigned int n2 = cnt >> 1;
        for (unsigned int i = t; i < n2; i += 1024u) {
            ulonglong2 v = p2[i];
            VU_ACC(v.x); VU_ACC(v.y);
        }
        if (t == 0 && (cnt & 1u)) {
            unsigned long long v = p[cnt - 1];
            VU_ACC(v);
        }
    }
#undef VU_ACC
    __syncthreads();

    if (iv0 < nv) {
        obuf[3 * t + 0] = va0.x;
        obuf[3 * t + 1] = va0.y;
        obuf[3 * t + 2] = va0.x - acc[t];
    }
    {
        int i2 = t + 1024;
        if (iv1 < nv) {
            obuf[3 * i2 + 0] = va1.x;
            obuf[3 * i2 + 1] = va1.y;
            obuf[3 * i2 + 2] = va1.x - acc[i2];
        }
    }
    __syncthreads();

    // coalesced float4 write of the bucket's contiguous out-slice
    long fbase = (long)q * (BSIZE * 3);
    int nfl = 3 * nv - (int)fbase;
    if (nfl > BSIZE * 3) nfl = BSIZE * 3;
    if (nfl > 0) {
        float4* o4 = (float4*)(out + fbase);       // fbase mult of 4
        const float4* s4 = (const float4*)obuf;
        int n4 = nfl >> 2;
        for (int j = t; j < n4; j += 1024) o4[j] = s4[j];
        for (int j = (n4 << 2) + t; j < nfl; j += 1024) out[fbase + j] = obuf[j];
    }
}

// ---- fallback (round-1 path, 961 us) if ws is too small ----
__global__ void vu_init_kernel(const float* __restrict__ vattr,
                               float* __restrict__ out, int n) {
    int i = blockIdx.x * blockDim.x + threadIdx.x;
    if (i < n) {
        float2 v = ((const float2*)vattr)[i];
        out[3 * i + 0] = v.x;
        out[3 * i + 1] = v.y;
        out[3 * i + 2] = v.x;
    }
}

__global__ void vu_scatter_kernel(const int* __restrict__ src,
                                  const float* __restrict__ eattr,
                                  float* __restrict__ out, int ne) {
    int t = blockIdx.x * blockDim.x + threadIdx.x;
    int e0 = t * 4;
    if (e0 + 3 < ne) {
        int4 idx = ((const int4*)src)[t];
        float4 a = ((const float4*)eattr)[2 * t + 0];
        float4 b = ((const float4*)eattr)[2 * t + 1];
        atomicAdd(&out[3 * idx.x + 2], -a.y);
        atomicAdd(&out[3 * idx.y + 2], -a.w);
        atomicAdd(&out[3 * idx.z + 2], -b.y);
        atomicAdd(&out[3 * idx.w + 2], -b.w);
    } else {
        for (int e = e0; e < ne; ++e)
            atomicAdd(&out[3 * src[e] + 2], -eattr[2 * e + 1]);
    }
}

extern "C" void kernel_launch(void* const* d_in, const int* in_sizes, int n_in,
                              void* d_out, int out_size, void* d_ws, size_t ws_size,
                              hipStream_t stream) {
    const float* vattr = (const float*)d_in[0];
    const int* edges = (const int*)d_in[1];   // (2, N_E); row 0 = src
    const float* eattr = (const float*)d_in[2];
    float* out = (float*)d_out;

    int nv = in_sizes[0] / 2;   // 1,000,000
    int ne = in_sizes[2] / 2;   // 16,000,000

    int nbuck = (nv + BSIZE - 1) >> BSHIFT;          // 489
    int mean_r = ne / nbuck / NREP;                  // ~4090
    int cap_r = mean_r + mean_r / 8;                 // ~+12.5% (~8 sigma)
    cap_r = (cap_r + 15) & ~15;                      // 4608

    size_t alloc_bytes = (size_t)NREP * NBUCK_PAD * 4;   // 16 KB
    size_t pair_bytes = (size_t)nbuck * NREP * (size_t)cap_r * 8ull;
    size_t need = alloc_bytes + pair_bytes;          // ~144 MB

    if (ws_size >= need && nbuck <= NBUCK_PAD) {
        unsigned int* alloc = (unsigned int*)d_ws;
        unsigned long long* pairs = (unsigned long long*)((char*)d_ws + alloc_bytes);
        (void)hipMemsetAsync(alloc, 0, alloc_bytes, stream);

        int nt_tiles = (ne + TILE - 1) / TILE;       // 1954
        int grid = PGRID; if (grid > nt_tiles) grid = nt_tiles;
        vu_partition<<<grid, TPB, 0, stream>>>(edges, eattr, pairs, alloc,
                                               ne, nbuck, cap_r);
        vu_aggregate<<<nbuck, 1024, 0, stream>>>(pairs, alloc, vattr, out,
                                                 nv, cap_r);
    } else {
        int threads = 256;
        int blocks = (nv + threads - 1) / threads;
        vu_init_kernel<<<blocks, threads, 0, stream>>>(vattr, out, nv);
        int nt = (ne + 3) / 4;
        blocks = (nt + threads - 1) / threads;
        vu_scatter_kernel<<<blocks, threads, 0, stream>>>(edges, eattr, out, ne);
    }
}

// Round 4
// 366.933 us; speedup vs baseline: 1.0816x; 1.0174x over previous
//
#include <hip/hip_runtime.h>

// VertexUpdate: out[i] = (b_i, x_i, b_i - sum_{e:src[e]=i} c_e)
//
// R1: device atomicAdd scatter -> 771 us; WRITE 500 MB (16M x 32B sectors).
// R4: radix binning, cursor scatter -> 640 us (partition WRITE 455 MB).
// R5: LDS counting-sort + linear copy-out -> 429 us.
// R6: TPB 1024, register-staged vector loads, ulonglong2 aggregate -> 401 us.
// R7: shuffle wave-scan (18 barriers -> 5), early eattr loads -> 390 us.
// R8: persistent blocks + cross-barrier register prefetch -> FLAT.
// R9: 8-replica alloc counters + replica pair regions (cross-XCD atomic
//     contention) -> 373 us; partition 106 us @ 28% HBM, VALU 12%.
//     VGPR_Count=32 proves the R8 prefetch never survived compilation:
//     32 live data regs can't fit 32 VGPRs -> compiler sank the prefetch
//     loads to their use point, deleting the pipeline (null explained).
// R10: TLP instead of ILP (m114: wave-level overlap beats source
//     pipelining). Single-shot blocks: TPB 512, TILE 4096, natural grid
//     3907, no prefetch/persistence. LDS 39 KB (gbase merged into dead
//     hist[]) -> 4 blocks/CU = 32 waves/CU; 4 staggered block-pipelines
//     per CU cover each other's scan/scatter phases. Accepted cost:
//     bucket runs 16.8 -> 8.4 entries, WRITE ~135 -> ~190 MB.
//     Aggregate frozen (R9). Predict: partition ~70 us, VGPR ~44,
//     occ >=85%, total ~335 us. If flat: ablation round next.

#define BSHIFT 11
#define BSIZE (1 << BSHIFT)      // 2048 vertices per bucket
#define NBUCK_PAD 512            // padded bucket count (real: 489)
#define TILE 4096
#define TPB 512                  // == NBUCK_PAD: one bucket per thread
#define NREP 8                   // replica sets (one per XCD)

// Barrier that does NOT drain vmcnt: LDS ordering only (global atomic
// results are waited on at their use, not at barriers).
#define BARL() do { \
    asm volatile("s_waitcnt lgkmcnt(0)" ::: "memory"); \
    __builtin_amdgcn_s_barrier(); } while (0)

__global__ __launch_bounds__(TPB, 8)
void vu_partition(const int* __restrict__ src,
                  const float* __restrict__ eattr,
                  unsigned long long* __restrict__ pairs,
                  unsigned int* __restrict__ alloc,
                  int ne, int nbuck, int cap_r) {
    __shared__ unsigned long long sorted[TILE];   // 32 KB
    __shared__ unsigned int hist[NBUCK_PAD];      // becomes gbase after scan
    __shared__ unsigned int base_l[NBUCK_PAD];
    __shared__ unsigned int cursor[NBUCK_PAD];
    __shared__ unsigned int wsum[8];              // per-wave scan sums
    // total ~38.1 KB -> 4 blocks/CU

    const int t = threadIdx.x;
    const int rep = blockIdx.x & (NREP - 1);      // replica set (~XCD id)
    const int tile0 = blockIdx.x * TILE;
    int lim = ne - tile0; if (lim > TILE) lim = TILE;
    const bool full = (lim == TILE);

    hist[t] = 0u;                                 // TPB == NBUCK_PAD
    BARL();                                       // B0: hist zeroed

    // --- 1) vector load (thread t owns edges tile0+8t .. 8t+7) + hist ---
    int4 sa, sb;
    float c0, c1, c2, c3, c4, c5, c6, c7;
    if (full) {
        const int4* s4 = (const int4*)(src + tile0) + 2 * t;
        sa = s4[0];                               // edges 8t..8t+3
        sb = s4[1];                               // edges 8t+4..8t+7
        const float4* e4 = (const float4*)(eattr + 2 * (size_t)tile0) + 4 * t;
        float4 e0 = e4[0], e1 = e4[1], e2 = e4[2], e3 = e4[3];
        c0 = e0.y; c1 = e0.w; c2 = e1.y; c3 = e1.w;
        c4 = e2.y; c5 = e2.w; c6 = e3.y; c7 = e3.w;
        atomicAdd(&hist[((unsigned)sa.x) >> BSHIFT], 1u);
        atomicAdd(&hist[((unsigned)sa.y) >> BSHIFT], 1u);
        atomicAdd(&hist[((unsigned)sa.z) >> BSHIFT], 1u);
        atomicAdd(&hist[((unsigned)sa.w) >> BSHIFT], 1u);
        atomicAdd(&hist[((unsigned)sb.x) >> BSHIFT], 1u);
        atomicAdd(&hist[((unsigned)sb.y) >> BSHIFT], 1u);
        atomicAdd(&hist[((unsigned)sb.z) >> BSHIFT], 1u);
        atomicAdd(&hist[((unsigned)sb.w) >> BSHIFT], 1u);
    } else {
        for (int i = t; i < lim; i += TPB)
            atomicAdd(&hist[((unsigned)src[tile0 + i]) >> BSHIFT], 1u);
    }
    BARL();                                       // B1: hist complete

    unsigned int mycnt = hist[t];
    // replica-local allocation atomic; latency hides under the scan,
    // waited at the hist[t]=gb use (BARL never drains vmcnt).
    unsigned int gb = 0u;
    if (t < nbuck && mycnt)
        gb = atomicAdd(&alloc[rep * NBUCK_PAD + t], mycnt);

    // --- 2) exclusive scan over 512 buckets (shuffle wave-scan) ---
    unsigned int x = mycnt;
    #pragma unroll
    for (int off = 1; off < 64; off <<= 1) {
        unsigned int v = __shfl_up(x, off, 64);
        if ((t & 63) >= off) x += v;
    }
    if ((t & 63) == 63) wsum[t >> 6] = x;
    BARL();                                       // B2: wsum ready

    unsigned int wx = 0u;
    int wid = t >> 6;
    #pragma unroll
    for (int k = 0; k < 7; ++k) {                 // redundant per-thread prefix
        unsigned int w = wsum[k];
        if (k < wid) wx += w;
    }
    unsigned int excl = x + wx - mycnt;
    base_l[t] = excl;
    cursor[t] = excl;
    hist[t] = gb;                                 // hist[] now holds gbase
    BARL();                                       // B3: cursors ready

    // --- 3) scatter into LDS sorted by bucket ---
#define VU_SCAT(sv, cv) do { \
        unsigned int q_ = ((unsigned)(sv)) >> BSHIFT; \
        unsigned int pos_ = atomicAdd(&cursor[q_], 1u); \
        sorted[pos_] = ((unsigned long long)__float_as_uint(cv) << 32) \
                       | (unsigned)(sv); } while (0)
    if (full) {
        VU_SCAT(sa.x, c0); VU_SCAT(sa.y, c1);
        VU_SCAT(sa.z, c2); VU_SCAT(sa.w, c3);
        VU_SCAT(sb.x, c4); VU_SCAT(sb.y, c5);
        VU_SCAT(sb.z, c6); VU_SCAT(sb.w, c7);
    } else {
        for (int i = t; i < lim; i += TPB) {
            int e = tile0 + i;
            int s = src[e];
            float2 ec = ((const float2*)eattr)[e];
            VU_SCAT(s, ec.y);
        }
    }
#undef VU_SCAT
    BARL();                                       // B4: sorted ready

    // --- 4) linear copy-out into this block's replica region ---
    for (int i = t; i < lim; i += TPB) {
        unsigned long long p = sorted[i];
        unsigned int q = ((unsigned int)p) >> BSHIFT;
        unsigned int seg = (q << 3) + (unsigned int)rep;      // q*NREP+rep
        unsigned int dst = seg * (unsigned int)cap_r + hist[q]
                         + ((unsigned int)i - base_l[q]);
        unsigned int hi = seg * (unsigned int)cap_r + (unsigned int)cap_r - 1u;
        if (dst > hi) dst = hi;                    // OOB guard (never fires)
        pairs[dst] = p;
    }
}

__global__ __launch_bounds__(1024)
void vu_aggregate(const unsigned long long* __restrict__ pairs,
                  const unsigned int* __restrict__ alloc,
                  const float* __restrict__ vattr,
                  float* __restrict__ out,
                  int nv, int cap_r) {
    __shared__ float acc[BSIZE];                   // 8 KB
    __shared__ float obuf[BSIZE * 3];              // 24 KB
    int q = blockIdx.x;
    int t = threadIdx.x;
    acc[t] = 0.0f;
    acc[t + 1024] = 0.0f;

    // early vattr loads: latency hides under the pair loops
    int v0 = q << BSHIFT;
    int iv0 = v0 + t, iv1 = v0 + t + 1024;
    float2 va0 = make_float2(0.f, 0.f), va1 = make_float2(0.f, 0.f);
    if (iv0 < nv) va0 = ((const float2*)vattr)[iv0];
    if (iv1 < nv) va1 = ((const float2*)vattr)[iv1];

    // preload all replica counts
    unsigned int cnts[NREP];
    #pragma unroll
    for (int r = 0; r < NREP; ++r) {
        unsigned int c = alloc[r * NBUCK_PAD + q];
        cnts[r] = (c > (unsigned int)cap_r) ? (unsigned int)cap_r : c;
    }
    __syncthreads();

#define VU_ACC(v64) do { \
        atomicAdd(&acc[((unsigned int)(v64)) & (BSIZE - 1)], \
                  __uint_as_float((unsigned int)((v64) >> 32))); } while (0)

    #pragma unroll
    for (int r = 0; r < NREP; ++r) {
        unsigned int cnt = cnts[r];
        const unsigned long long* p =
            pairs + (size_t)(q * NREP + r) * (size_t)cap_r;
        const ulonglong2* p2 = (const ulonglong2*)p;  // cap_r mult of 16
        unsigned int n2 = cnt >> 1;
        for (unsigned int i = t; i < n2; i += 1024u) {
            ulonglong2 v = p2[i];
            VU_ACC(v.x); VU_ACC(v.y);
        }
        if (t == 0 && (cnt & 1u)) {
            unsigned long long v = p[cnt - 1];
            VU_ACC(v);
        }
    }
#undef VU_ACC
    __syncthreads();

    if (iv0 < nv) {
        obuf[3 * t + 0] = va0.x;
        obuf[3 * t + 1] = va0.y;
        obuf[3 * t + 2] = va0.x - acc[t];
    }
    {
        int i2 = t + 1024;
        if (iv1 < nv) {
            obuf[3 * i2 + 0] = va1.x;
            obuf[3 * i2 + 1] = va1.y;
            obuf[3 * i2 + 2] = va1.x - acc[i2];
        }
    }
    __syncthreads();

    // coalesced float4 write of the bucket's contiguous out-slice
    long fbase = (long)q * (BSIZE * 3);
    int nfl = 3 * nv - (int)fbase;
    if (nfl > BSIZE * 3) nfl = BSIZE * 3;
    if (nfl > 0) {
        float4* o4 = (float4*)(out + fbase);       // fbase mult of 4
        const float4* s4 = (const float4*)obuf;
        int n4 = nfl >> 2;
        for (int j = t; j < n4; j += 1024) o4[j] = s4[j];
        for (int j = (n4 << 2) + t; j < nfl; j += 1024) out[fbase + j] = obuf[j];
    }
}

// ---- fallback (round-1 path, 961 us) if ws is too small ----
__global__ void vu_init_kernel(const float* __restrict__ vattr,
                               float* __restrict__ out, int n) {
    int i = blockIdx.x * blockDim.x + threadIdx.x;
    if (i < n) {
        float2 v = ((const float2*)vattr)[i];
        out[3 * i + 0] = v.x;
        out[3 * i + 1] = v.y;
        out[3 * i + 2] = v.x;
    }
}

__global__ void vu_scatter_kernel(const int* __restrict__ src,
                                  const float* __restrict__ eattr,
                                  float* __restrict__ out, int ne) {
    int t = blockIdx.x * blockDim.x + threadIdx.x;
    int e0 = t * 4;
    if (e0 + 3 < ne) {
        int4 idx = ((const int4*)src)[t];
        float4 a = ((const float4*)eattr)[2 * t + 0];
        float4 b = ((const float4*)eattr)[2 * t + 1];
        atomicAdd(&out[3 * idx.x + 2], -a.y);
        atomicAdd(&out[3 * idx.y + 2], -a.w);
        atomicAdd(&out[3 * idx.z + 2], -b.y);
        atomicAdd(&out[3 * idx.w + 2], -b.w);
    } else {
        for (int e = e0; e < ne; ++e)
            atomicAdd(&out[3 * src[e] + 2], -eattr[2 * e + 1]);
    }
}

extern "C" void kernel_launch(void* const* d_in, const int* in_sizes, int n_in,
                              void* d_out, int out_size, void* d_ws, size_t ws_size,
                              hipStream_t stream) {
    const float* vattr = (const float*)d_in[0];
    const int* edges = (const int*)d_in[1];   // (2, N_E); row 0 = src
    const float* eattr = (const float*)d_in[2];
    float* out = (float*)d_out;

    int nv = in_sizes[0] / 2;   // 1,000,000
    int ne = in_sizes[2] / 2;   // 16,000,000

    int nbuck = (nv + BSIZE - 1) >> BSHIFT;          // 489
    int mean_r = ne / nbuck / NREP;                  // ~4090
    int cap_r = mean_r + mean_r / 8;                 // ~+12.5% (~8 sigma)
    cap_r = (cap_r + 15) & ~15;                      // 4608

    size_t alloc_bytes = (size_t)NREP * NBUCK_PAD * 4;   // 16 KB
    size_t pair_bytes = (size_t)nbuck * NREP * (size_t)cap_r * 8ull;
    size_t need = alloc_bytes + pair_bytes;          // ~144 MB

    if (ws_size >= need && nbuck <= NBUCK_PAD) {
        unsigned int* alloc = (unsigned int*)d_ws;
        unsigned long long* pairs = (unsigned long long*)((char*)d_ws + alloc_bytes);
        (void)hipMemsetAsync(alloc, 0, alloc_bytes, stream);

        int nt_tiles = (ne + TILE - 1) / TILE;       // 3907
        vu_partition<<<nt_tiles, TPB, 0, stream>>>(edges, eattr, pairs, alloc,
                                                   ne, nbuck, cap_r);
        vu_aggregate<<<nbuck, 1024, 0, stream>>>(pairs, alloc, vattr, out,
                                                 nv, cap_r);
    } else {
        int threads = 256;
        int blocks = (nv + threads - 1) / threads;
        vu_init_kernel<<<blocks, threads, 0, stream>>>(vattr, out, nv);
        int nt = (ne + 3) / 4;
        blocks = (nt + threads - 1) / threads;
        vu_scatter_kernel<<<blocks, threads, 0, stream>>>(edges, eattr, out, ne);
    }
}